// Round 1
// 255.693 us; speedup vs baseline: 1.0775x; 1.0775x over previous
//
#include <hip/hip_runtime.h>
#include <stdint.h>

#define S_LEN  1500
#define S_PAD  1536
#define BATCH  4
#define NSTATE 1024
#define NHEAD  16
#define HDIM   64
#define MROWS  6000   // BATCH * S_LEN
#define C1 0.180336879f   // 0.125 * log2(e)

typedef __attribute__((ext_vector_type(8)))  short short8;    // 8 bf16 = 4 VGPRs
typedef __attribute__((ext_vector_type(4)))  float floatx4;
typedef __attribute__((ext_vector_type(16))) float floatx16;

__device__ __forceinline__ unsigned short f2bf(float f) {
  union { float f; unsigned int u; } v; v.f = f;
  unsigned int r = v.u + 0x7fffu + ((v.u >> 16) & 1u);
  return (unsigned short)(r >> 16);
}

// async global->LDS, 16B per lane: lane i reads its own global addr, writes
// wave-uniform LDS base + i*16.
__device__ __forceinline__ void gld_lds16(const void* g, void* l) {
  __builtin_amdgcn_global_load_lds(
      (const __attribute__((address_space(1))) void*)g,
      (__attribute__((address_space(3))) void*)l, 16, 0, 0);
}

// ---------------------------------------------------------------------------
// fp32 -> bf16 for x + 4 weight matrices, one launch.
// ---------------------------------------------------------------------------
__global__ __launch_bounds__(256) void cvt_all(
    const float* __restrict__ x,  const float* __restrict__ Wq,
    const float* __restrict__ Wk, const float* __restrict__ Wv,
    const float* __restrict__ Wo, unsigned short* __restrict__ dst)
{
  const size_t NX = (size_t)MROWS * NSTATE;
  size_t e = ((size_t)blockIdx.x * 256 + threadIdx.x) * 4;
  const float* src; size_t off;
  if (e < NX) { src = x; off = e; }
  else {
    size_t t = e - NX;
    int wsel = (int)(t >> 20);           // NW = 2^20
    off = t & ((1u << 20) - 1);
    src = (wsel == 0) ? Wq : (wsel == 1) ? Wk : (wsel == 2) ? Wv : Wo;
  }
  float4 v = *(const float4*)(src + off);
  uint2 o;
  o.x = (unsigned int)f2bf(v.x) | ((unsigned int)f2bf(v.y) << 16);
  o.y = (unsigned int)f2bf(v.z) | ((unsigned int)f2bf(v.w) << 16);
  *(uint2*)(dst + e) = o;
}

// ---------------------------------------------------------------------------
// GEMM: Y[m,n] = (sum_k X[m,k]*W[n,k] + bias) * oscale; bf16 in, fp32 accum.
// 128x128 tile, 4 waves, BK=64 as two m97-layout BK=32 half-buffers.
// ---------------------------------------------------------------------------
template <bool F32OUT>
__device__ __forceinline__ void gemm128_bt(
    const unsigned short* __restrict__ X,
    const unsigned short* __restrict__ W,
    const float* __restrict__ bias,
    void* __restrict__ Yv,
    int m0, int n0, float oscale)
{
  __shared__ unsigned short As[2][128 * 32];   // 8 KB each
  __shared__ unsigned short Bs[2][128 * 32];

  const int tid  = threadIdx.x;
  const int lane = tid & 63;
  const int wid  = tid >> 6;
  const int wm   = (wid & 1) * 64;
  const int wn   = (wid >> 1) * 64;
  const int l15  = lane & 15;
  const int l4   = lane >> 4;

  floatx4 acc[4][4];
#pragma unroll
  for (int i = 0; i < 4; ++i)
#pragma unroll
    for (int j = 0; j < 4; ++j)
      acc[i][j] = (floatx4){0.f, 0.f, 0.f, 0.f};

  const int srow  = tid >> 2;        // 0..63
  const int scolb = (tid & 3) * 16;  // byte offset within 64B K-row

  const char* xrp[2];
  const char* wrp[2];
#pragma unroll
  for (int r = 0; r < 2; ++r) {
    int arow = m0 + r * 64 + srow;
    if (arow > MROWS - 1) arow = MROWS - 1;
    xrp[r] = (const char*)X + (size_t)arow * NSTATE * 2 + scolb;
    int brow = n0 + r * 64 + srow;   // N=1024 always full
    wrp[r] = (const char*)W + (size_t)brow * NSTATE * 2 + scolb;
  }

  for (int k0 = 0; k0 < NSTATE; k0 += 64) {
    __syncthreads();   // previous pair of half-tiles fully consumed
#pragma unroll
    for (int h = 0; h < 2; ++h) {
      int kb = (k0 + h * 32) * 2;    // byte offset along K
#pragma unroll
      for (int r = 0; r < 2; ++r) {
        gld_lds16(xrp[r] + kb, (char*)As[h] + r * 4096 + wid * 1024);
        gld_lds16(wrp[r] + kb, (char*)Bs[h] + r * 4096 + wid * 1024);
      }
    }
    __syncthreads();   // staging visible

#pragma unroll
    for (int h = 0; h < 2; ++h) {
      short8 a[4], b[4];
#pragma unroll
      for (int i = 0; i < 4; ++i)
        a[i] = *(const short8*)(As[h] + (wm + i * 16 + l15) * 32 + l4 * 8);
#pragma unroll
      for (int j = 0; j < 4; ++j)
        b[j] = *(const short8*)(Bs[h] + (wn + j * 16 + l15) * 32 + l4 * 8);
#pragma unroll
      for (int i = 0; i < 4; ++i)
#pragma unroll
        for (int j = 0; j < 4; ++j)
          acc[i][j] = __builtin_amdgcn_mfma_f32_16x16x32_bf16(a[i], b[j], acc[i][j], 0, 0, 0);
    }
  }

  // epilogue: C/D layout row=(lane>>4)*4+r, col=lane&15
#pragma unroll
  for (int j = 0; j < 4; ++j) {
    int ng = n0 + wn + j * 16 + l15;
    float bias_v = bias ? bias[ng] : 0.f;
#pragma unroll
    for (int i = 0; i < 4; ++i) {
      int mgb = m0 + wm + i * 16 + l4 * 4;
#pragma unroll
      for (int r = 0; r < 4; ++r) {
        int mg = mgb + r;
        if (mg < MROWS) {
          float val = (acc[i][j][r] + bias_v) * oscale;
          if (F32OUT) ((float*)Yv)[(size_t)mg * NSTATE + ng] = val;
          else        ((unsigned short*)Yv)[(size_t)mg * NSTATE + ng] = f2bf(val);
        }
      }
    }
  }
}

// 1D grid, XCD-chunked swizzle (1128 = 8*141, bijective), N fastest so
// consecutive blocks on one XCD share the same X row-panel in its L2.
__global__ __launch_bounds__(256) void proj_qkv(
    const unsigned short* __restrict__ X,
    const unsigned short* __restrict__ Wq, const unsigned short* __restrict__ Wk,
    const unsigned short* __restrict__ Wv,
    const float* __restrict__ bq, const float* __restrict__ bv,
    unsigned short* __restrict__ q, unsigned short* __restrict__ k,
    unsigned short* __restrict__ v)
{
  const int id  = blockIdx.x;
  const int sid = (id & 7) * 141 + (id >> 3);
  const int z   = sid / 376;              // 47*8 blocks per matrix
  const int rem = sid - z * 376;
  const int m0  = (rem >> 3) * 128;
  const int n0  = (rem & 7) * 128;

  const unsigned short* W = (z == 0) ? Wq : (z == 1) ? Wk : Wv;
  const float* bias       = (z == 0) ? bq : (z == 1) ? (const float*)nullptr : bv;
  unsigned short* Y       = (z == 0) ? q  : (z == 1) ? k  : v;
  const float osc         = (z == 0) ? C1 : 1.0f;   // fold softmax scale into Q
  gemm128_bt<false>(X, W, bias, Y, m0, n0, osc);
}

__global__ __launch_bounds__(256) void proj_o(
    const unsigned short* __restrict__ X, const unsigned short* __restrict__ W,
    const float* __restrict__ bias, float* __restrict__ Y)
{
  const int id  = blockIdx.x;
  const int sid = (id & 7) * 47 + (id >> 3);   // 376 = 8*47, bijective
  gemm128_bt<true>(X, W, bias, Y, (sid >> 3) * 128, (sid & 7) * 128, 1.0f);
}

// ---------------------------------------------------------------------------
// V transpose: [B,S,H*D] -> Vt[B,H,D,S_PAD], zero-padded past S_LEN.
// ---------------------------------------------------------------------------
__global__ __launch_bounds__(256) void vtrans(
    const unsigned short* __restrict__ v, unsigned short* __restrict__ vt)
{
  __shared__ unsigned short T[64][72];
  const int tid = threadIdx.x;
  const int st = blockIdx.x * 64, h = blockIdx.y, b = blockIdx.z;
#pragma unroll
  for (int rr = 0; rr < 2; ++rr) {
    int sl = rr * 32 + (tid >> 3);
    int dl = (tid & 7) * 8;
    int s  = st + sl;
    uint4 val = make_uint4(0u, 0u, 0u, 0u);
    if (s < S_LEN)
      val = *(const uint4*)&v[((size_t)b * S_LEN + s) * NSTATE + h * HDIM + dl];
    *(uint4*)&T[sl][dl] = val;
  }
  __syncthreads();
#pragma unroll
  for (int rr = 0; rr < 2; ++rr) {
    int dl = rr * 32 + (tid >> 3);
    int s0 = (tid & 7) * 8;
    unsigned short tmp[8];
#pragma unroll
    for (int j2 = 0; j2 < 8; ++j2) tmp[j2] = T[s0 + j2][dl];
    *(uint4*)&vt[(((size_t)b * NHEAD + h) * HDIM + dl) * S_PAD + st + s0] =
        *(const uint4*)tmp;
  }
}

// ---------------------------------------------------------------------------
// Flash attention, transposed-score form (32x32x16 MFMA).
// Q is pre-scaled by 0.125*log2(e), so P = exp2(S) directly.
// P packed to bf16 with v_cvt_pk_bf16_f32 (RNE); l is computed on the MFMA
// pipe via an all-ones A operand (every output row of ones^T.P^T is the full
// column sum of the SAME bf16 P fed to PV -> exact normalization, no merge).
// ---------------------------------------------------------------------------
__global__ __launch_bounds__(256, 4) void attn32t(
    const unsigned short* __restrict__ Q, const unsigned short* __restrict__ K,
    const unsigned short* __restrict__ VT, unsigned short* __restrict__ O)
{
  __shared__ unsigned short SMEM[16384];      // 32 KB
  unsigned short* Ks  = SMEM;                 // [128 kv][64 d], 16B-chunk xor-swizzled
  unsigned short* Vts = SMEM + 8192;          // [64 d][128 kv], 16B-chunk xor-swizzled
  unsigned short* Os  = SMEM;                 // epilogue overlay [128 q][72]

  const int tid  = threadIdx.x;
  const int lane = tid & 63;
  const int w    = tid >> 6;
  const int l31  = lane & 31;
  const int lhi  = lane >> 5;

  // XCD-chunked swizzle (768 = 8*96): 12 consecutive blocks on one XCD share
  // the same (b,h) K/V panels in its private L2.
  const int id  = blockIdx.x;
  const int sid = (id & 7) * 96 + (id >> 3);
  const int qt  = sid % 12;
  const int hb  = sid / 12;
  const int h   = hb & 15;
  const int b   = hb >> 4;

  const size_t base  = ((size_t)b * S_LEN) * NSTATE + h * HDIM;
  const size_t vbase = (((size_t)b * NHEAD + h) * HDIM) * S_PAD;

  // Q fragments (B-operand): lane holds Q[q=l31][d = c*16 + lhi*8 + j]
  short8 qf[4];
  {
    int qrow = qt * 128 + w * 32 + l31;
    if (qrow > S_LEN - 1) qrow = S_LEN - 1;
    const unsigned short* qp = Q + base + (size_t)qrow * NSTATE;
#pragma unroll
    for (int c = 0; c < 4; ++c)
      qf[c] = *(const short8*)(qp + c * 16 + lhi * 8);
  }

  short8 ones8;
#pragma unroll
  for (int i = 0; i < 8; ++i) ones8[i] = (short)0x3F80;   // bf16 1.0

  floatx16 oacc[2];
  oacc[0] = (floatx16)(0.f);
  oacc[1] = (floatx16)(0.f);
  floatx16 lacc = (floatx16)(0.f);

  for (int t = 0; t < 12; ++t) {
    __syncthreads();   // previous tile fully consumed
    // stage K tile 128x64: call = 8 rows x 8 chunks, phys chunk = logical^(row&7)
#pragma unroll
    for (int qq = 0; qq < 4; ++qq) {
      int row  = (w * 4 + qq) * 8 + (lane >> 3);
      int logc = (lane & 7) ^ (row & 7);
      int s = t * 128 + row; if (s > S_LEN - 1) s = S_LEN - 1;
      gld_lds16(&K[base + (size_t)s * NSTATE + logc * 8],
                (char*)Ks + (w * 4 + qq) * 1024);
    }
    // stage Vt tile 64x128: call = 4 rows x 16 chunks, phys = logical^(d&7)
#pragma unroll
    for (int qq = 0; qq < 4; ++qq) {
      int d    = (w * 4 + qq) * 4 + (lane >> 4);
      int logc = (lane & 15) ^ (d & 7);
      gld_lds16(&VT[vbase + (size_t)d * S_PAD + t * 128 + logc * 8],
                (char*)Vts + (w * 4 + qq) * 1024);
    }
    __syncthreads();

#pragma unroll
    for (int kvt = 0; kvt < 4; ++kvt) {
      // --- S^T tile: 32 kv x 32 q (already in log2 units: Q pre-scaled) ---
      floatx16 sacc = (floatx16)(0.f);
#pragma unroll
      for (int c = 0; c < 4; ++c) {
        int row  = kvt * 32 + l31;
        int phys = (c * 2 + lhi) ^ (row & 7);
        short8 ak = *(const short8*)(Ks + row * 64 + phys * 8);
        sacc = __builtin_amdgcn_mfma_f32_32x32x16_bf16(ak, qf[c], sacc, 0, 0, 0);
      }

      // kv masking (only the last iteration's tail)
      if (t == 11 && kvt >= 2) {
        if (kvt == 3) {
#pragma unroll
          for (int r = 0; r < 16; ++r) sacc[r] = -3.0e38f;
        } else {
#pragma unroll
          for (int r = 12; r < 16; ++r) sacc[r] = lhi ? -3.0e38f : sacc[r];
        }
      }

      // p = exp2(s); pack bf16 pairs with RNE (one cvt_pk per pair)
      unsigned int pk[8], ex[8];
#pragma unroll
      for (int i = 0; i < 8; ++i) {
        float plo = exp2f(sacc[2 * i]);
        float phi = exp2f(sacc[2 * i + 1]);
        unsigned int rr;
        asm("v_cvt_pk_bf16_f32 %0, %1, %2" : "=v"(rr) : "v"(plo), "v"(phi));
        pk[i] = rr;
      }
#pragma unroll
      for (int i = 0; i < 8; ++i)
        ex[i] = __shfl_xor((unsigned int)pk[i], 32, 64);

      // P^T B-fragments (kv chunk 0: kv kvt*32+0..15; chunk 1: +16..31)
      int4 f0i, f1i;
      f0i.x = lhi ? ex[2] : pk[0];
      f0i.y = lhi ? ex[3] : pk[1];
      f0i.z = lhi ? pk[2] : ex[0];
      f0i.w = lhi ? pk[3] : ex[1];
      f1i.x = lhi ? ex[6] : pk[4];
      f1i.y = lhi ? ex[7] : pk[5];
      f1i.z = lhi ? pk[6] : ex[4];
      f1i.w = lhi ? pk[7] : ex[5];
      short8 f0 = *(short8*)&f0i;
      short8 f1 = *(short8*)&f1i;

      // l on the MFMA pipe: every row of (ones . P^T) is the full column sum
      lacc = __builtin_amdgcn_mfma_f32_32x32x16_bf16(ones8, f0, lacc, 0, 0, 0);
      lacc = __builtin_amdgcn_mfma_f32_32x32x16_bf16(ones8, f1, lacc, 0, 0, 0);

      // --- O^T += V^T P^T ---
#pragma unroll
      for (int dt = 0; dt < 2; ++dt) {
        int d = dt * 32 + l31;
        int p0 = ((kvt * 4 + 0) + lhi) ^ (d & 7);     // chunk16 idx = kc*2+lhi
        int p1 = ((kvt * 4 + 2) + lhi) ^ (d & 7);
        short8 av0 = *(const short8*)(Vts + d * 128 + p0 * 8);
        short8 av1 = *(const short8*)(Vts + d * 128 + p1 * 8);
        oacc[dt] = __builtin_amdgcn_mfma_f32_32x32x16_bf16(av0, f0, oacc[dt], 0, 0, 0);
        oacc[dt] = __builtin_amdgcn_mfma_f32_32x32x16_bf16(av1, f1, oacc[dt], 0, 0, 0);
      }
    }
  }

  // lacc[0] = sum over ALL kv of the bf16 P used in PV (same for both halves)
  float inv = 1.f / lacc[0];

  // epilogue: O^T regs -> LDS transpose -> coalesced global store
  __syncthreads();   // everyone done with Ks/Vts
#pragma unroll
  for (int dt = 0; dt < 2; ++dt)
#pragma unroll
    for (int g = 0; g < 4; ++g) {
      int d0 = dt * 32 + g * 8 + lhi * 4;
      float v0 = oacc[dt][4 * g + 0] * inv;
      float v1 = oacc[dt][4 * g + 1] * inv;
      float v2 = oacc[dt][4 * g + 2] * inv;
      float v3 = oacc[dt][4 * g + 3] * inv;
      uint2 pk2;
      pk2.x = (unsigned int)f2bf(v0) | ((unsigned int)f2bf(v1) << 16);
      pk2.y = (unsigned int)f2bf(v2) | ((unsigned int)f2bf(v3) << 16);
      *(uint2*)&Os[(w * 32 + l31) * 72 + d0] = pk2;
    }
  __syncthreads();
#pragma unroll
  for (int pass = 0; pass < 4; ++pass) {
    int e = pass * 256 + tid;
    int row = e >> 3, ch = e & 7;
    int s = qt * 128 + row;
    if (s < S_LEN)
      *(uint4*)&O[base + (size_t)s * NSTATE + ch * 8] = *(const uint4*)&Os[row * 72 + ch * 8];
  }
}

// ---------------------------------------------------------------------------
extern "C" void kernel_launch(void* const* d_in, const int* in_sizes, int n_in,
                              void* d_out, int out_size, void* d_ws, size_t ws_size,
                              hipStream_t stream) {
  const float* x  = (const float*)d_in[0];
  const float* Wq = (const float*)d_in[1];
  const float* bq = (const float*)d_in[2];
  const float* Wk = (const float*)d_in[3];
  const float* Wv = (const float*)d_in[4];
  const float* bv = (const float*)d_in[5];
  const float* Wo = (const float*)d_in[6];
  const float* bo = (const float*)d_in[7];
  float* out = (float*)d_out;

  const size_t NX = (size_t)MROWS * NSTATE;
  const size_t NW = (size_t)NSTATE * NSTATE;

  unsigned short* xb  = (unsigned short*)d_ws;   // dies after proj_qkv
  unsigned short* Wqb = xb  + NX;
  unsigned short* Wkb = Wqb + NW;
  unsigned short* Wvb = Wkb + NW;
  unsigned short* Wob = Wvb + NW;
  unsigned short* q   = Wob + NW;
  unsigned short* k   = q + NX;
  unsigned short* v   = k + NX;
  unsigned short* vt  = v + NX;
  unsigned short* wv  = xb;                      // alias onto dead xb

  dim3 blk(256);
  const size_t n4_total = (NX + 4 * NW) / 4;
  cvt_all<<<dim3((int)(n4_total / 256)), blk, 0, stream>>>(x, Wq, Wk, Wv, Wo, xb);
  proj_qkv<<<dim3(1128), blk, 0, stream>>>(xb, Wqb, Wkb, Wvb, bq, bv, q, k, v);
  vtrans<<<dim3(24, NHEAD, BATCH), blk, 0, stream>>>(v, vt);
  attn32t<<<dim3(768), blk, 0, stream>>>(q, k, vt, wv);
  proj_o<<<dim3(376), blk, 0, stream>>>(wv, Wob, bo, out);
}